// Round 5
// baseline (303.437 us; speedup 1.0000x reference)
//
#include <hip/hip_runtime.h>
#include <cmath>

#define IMG_W 512
#define IMG_H 512
#define NIMG 64
#define OWV 502   // valid-conv output extent (SSIM branch)

struct KTaps {
    float kw[11];   // normalized gaussian, win=11, sigma=1.5 (SSIM)
    float ke[13];   // erf-gaussian, 13 taps, NOT normalized (L1)
};

// ---------------- Kernel A: SSIM -> scalar sum ----------------
// Wave-private strips: each wave owns 64 output cols (+10 halo) x 64 output
// rows and marches 74 input rows with a private LDS double-buffer. ZERO
// __syncthreads in the whole kernel — waves are fully independent streams.
// Mod-11 register pending accumulators do the vertical filter.
__global__ __launch_bounds__(256) void ssim_band_kernel(
        const float* __restrict__ x, const float* __restrict__ y,
        double* __restrict__ ssum, KTaps kt) {
    __shared__ __align__(16) float sx[4][2][80];   // [wave][buf][76 used]
    __shared__ __align__(16) float sy[4][2][80];

    const int tid  = threadIdx.x;
    const int wv   = tid >> 6;
    const int lane = tid & 63;
    const int task = blockIdx.x * 4 + wv;     // 0..4095
    const int img   = task >> 6;
    const int strip = (task >> 3) & 7;        // 0..7 -> 64-col strips
    const int band  = task & 7;               // 0..7 -> 64-row bands
    const int r0 = band * 64;
    const int c0 = strip * 64;

    const float* __restrict__ xi = x + (size_t)img * IMG_H * IMG_W;
    const float* __restrict__ yi = y + (size_t)img * IMG_H * IMG_W;

    // staging role: lanes 0..18 load x (19 float4 = 76 cols), 19..37 load y
    const bool st_act = (lane < 38);
    const bool st_x   = (lane < 19);
    const int  st_k   = st_x ? lane : lane - 19;
    const int  st_g   = c0 + 4 * st_k;        // global col of this lane's f4
    const float* __restrict__ st_arr = st_x ? xi : yi;

    auto ldrow = [&](int r) -> float4 {       // zero OOB (feeds masked outputs)
        float4 v = make_float4(0.f, 0.f, 0.f, 0.f);
        if (st_act && r < IMG_H && st_g < IMG_W)
            v = *(const float4*)(st_arr + (size_t)r * IMG_W + st_g);
        return v;
    };
    auto strow = [&](int b, float4 v) {
        if (st_act) {
            float* dst = st_x ? &sx[wv][b][4 * st_k] : &sy[wv][b][4 * st_k];
            *(float4*)dst = v;
        }
    };

    // parity-resolved 12-tap weights (window read is f2-aligned from even base)
    float w12[12];
#pragma unroll
    for (int j = 0; j < 12; ++j) w12[j] = 0.f;
    if (lane & 1) {
#pragma unroll
        for (int j = 0; j < 11; ++j) w12[j + 1] = kt.kw[j];
    } else {
#pragma unroll
        for (int j = 0; j < 11; ++j) w12[j] = kt.kw[j];
    }

    float acc[11][5];
#pragma unroll
    for (int i = 0; i < 11; ++i)
#pragma unroll
        for (int q = 0; q < 5; ++q) acc[i][q] = 0.f;
    float tsum = 0.f;

    const int basei = lane & ~1;
    const int outc  = c0 + lane;

    strow(0, ldrow(r0));    // stage first row -> buf 0 (in-order DS pipe)

#pragma unroll 1
    for (int chunk = 0; chunk < 7; ++chunk) {
#pragma unroll
        for (int p = 0; p < 11; ++p) {
            const int rr = chunk * 11 + p;
            if (rr <= 73) {
                const int b = rr & 1;
                // prefetch next row into regs (hidden under this row's compute)
                float4 pv = make_float4(0.f, 0.f, 0.f, 0.f);
                const bool pre = (rr < 73);
                if (pre) pv = ldrow(r0 + rr + 1);

                // fused h-pass: 12-value window, 5 quantities
                float xv[12], yv[12];
#pragma unroll
                for (int j = 0; j < 6; ++j) {
                    const float2 a = *(const float2*)&sx[wv][b][basei + 2 * j];
                    const float2 c = *(const float2*)&sy[wv][b][basei + 2 * j];
                    xv[2 * j] = a.x; xv[2 * j + 1] = a.y;
                    yv[2 * j] = c.x; yv[2 * j + 1] = c.y;
                }
                float h0 = 0.f, h1 = 0.f, h2 = 0.f, h3 = 0.f, h4 = 0.f;
#pragma unroll
                for (int j = 0; j < 12; ++j) {
                    const float w = w12[j];
                    const float a = xv[j], bb = yv[j];
                    h0 += w * a;
                    h1 += w * bb;
                    h2 += w * (a * a);
                    h3 += w * (bb * bb);
                    h4 += w * (a * bb);
                }
                // v-pass: 55 FMAs into mod-11 pending slots (static indices)
#pragma unroll
                for (int d = 0; d <= 10; ++d) {
                    const int s = (p + 11 - d) % 11;
                    const float w = kt.kw[d];
                    acc[s][0] += w * h0; acc[s][1] += w * h1; acc[s][2] += w * h2;
                    acc[s][3] += w * h3; acc[s][4] += w * h4;
                }
                {   // slot (p+1)%11 completed output row ro = rr-10
                    const int sc = (p + 1) % 11;
                    const int ro = rr - 10;
                    if (ro >= 0) {
                        const int o = r0 + ro;
                        if (o < OWV && outc < OWV) {
                            const float mx = acc[sc][0], my = acc[sc][1];
                            const float vx = acc[sc][2] - mx * mx;
                            const float vy = acc[sc][3] - my * my;
                            const float cov = acc[sc][4] - mx * my;
                            const float c1 = 1e-4f, c2 = 9e-4f;
                            tsum += ((2.f * mx * my + c1) * (2.f * cov + c2)) /
                                    ((mx * mx + my * my + c1) * (vx + vy + c2));
                        }
                    }
#pragma unroll
                    for (int q = 0; q < 5; ++q) acc[sc][q] = 0.f;   // ALWAYS reset
                }
                if (pre) strow(b ^ 1, pv);   // no barrier: wave-private buffer
            }
        }
    }

    // per-wave shuffle reduce -> one atomic per wave (4096 total)
#pragma unroll
    for (int off = 32; off > 0; off >>= 1) tsum += __shfl_down(tsum, off, 64);
    if (lane == 0) atomicAdd(ssum, (double)tsum);
}

// ---------------- Kernel B: L1 map + combine ----------------
// Wave-private 128-col strips, 2 cols/lane, mod-13 pending accumulators,
// zero barriers. SAME zero-pad via zeroed OOB staging.
__global__ __launch_bounds__(256) void l1_band_kernel(
        const float* __restrict__ x, const float* __restrict__ y,
        const double* __restrict__ ssum, float* __restrict__ out, KTaps kt) {
    __shared__ __align__(16) float sd[4][2][144];   // [wave][buf][144 staged]

    const int tid  = threadIdx.x;
    const int wv   = tid >> 6;
    const int lane = tid & 63;
    const int task = blockIdx.x * 4 + wv;     // 0..4095
    const int img   = task >> 6;
    const int rem   = task & 63;
    const int strip = rem >> 4;               // 0..3 -> 128-col strips
    const int band  = rem & 15;               // 0..15 -> 32-row bands
    const int C    = strip * 128;
    const int o0   = band * 32;
    const int rin0 = o0 - 6;

    const float* __restrict__ xi = x + (size_t)img * IMG_H * IMG_W;
    const float* __restrict__ yi = y + (size_t)img * IMG_H * IMG_W;
    float* __restrict__ oi = out + (size_t)img * IMG_H * IMG_W;

    const float base = 100.f * 0.84f * (1.f - (float)(*ssum) * (1.f / 16128256.f));

    // staging: lanes 0..35 load f4 of d = y-x at global col C-8+4*lane
    const bool st_act = (lane < 36);
    const int  st_g   = C - 8 + 4 * lane;
    auto ldrow = [&](int r) -> float4 {       // zero pad rows/cols (SAME conv)
        float4 v = make_float4(0.f, 0.f, 0.f, 0.f);
        if (st_act && r >= 0 && r < IMG_H && st_g >= 0 && st_g < IMG_W) {
            const float4 a  = *(const float4*)(xi + (size_t)r * IMG_W + st_g);
            const float4 bb = *(const float4*)(yi + (size_t)r * IMG_W + st_g);
            v = make_float4(bb.x - a.x, bb.y - a.y, bb.z - a.z, bb.w - a.w);
        }
        return v;
    };
    auto strow = [&](int b, float4 v) {
        if (st_act) *(float4*)&sd[wv][b][4 * lane] = v;
    };

    float acc[13][2];
#pragma unroll
    for (int i = 0; i < 13; ++i) { acc[i][0] = 0.f; acc[i][1] = 0.f; }

    strow(0, ldrow(rin0));

#pragma unroll 1
    for (int chunk = 0; chunk < 4; ++chunk) {
#pragma unroll
        for (int p = 0; p < 13; ++p) {
            const int rr = chunk * 13 + p;
            if (rr <= 43) {
                const int b = rr & 1;
                float4 pv = make_float4(0.f, 0.f, 0.f, 0.f);
                const bool pre = (rr < 43);
                if (pre) pv = ldrow(rin0 + rr + 1);

                // h-pass: 14-value window serves this lane's 2 cols.
                // out col c = C+2*lane+{0,1}; window col c-6..c+6 ->
                // LDS idx (col-(C-8)) = 2*lane+2 .. 2*lane+15 (f2-aligned).
                float dv[14];
#pragma unroll
                for (int j = 0; j < 7; ++j) {
                    const float2 a = *(const float2*)&sd[wv][b][2 * lane + 2 + 2 * j];
                    dv[2 * j] = a.x; dv[2 * j + 1] = a.y;
                }
                float a0 = 0.f, a1 = 0.f;
#pragma unroll
                for (int u = 0; u < 13; ++u) {
                    a0 += kt.ke[u] * dv[u];
                    a1 += kt.ke[u] * dv[u + 1];
                }
                // v-pass into mod-13 pending slots
#pragma unroll
                for (int dd = 0; dd <= 12; ++dd) {
                    const int s = (p + 13 - dd) % 13;
                    acc[s][0] += kt.ke[dd] * a0;
                    acc[s][1] += kt.ke[dd] * a1;
                }
                {
                    const int sc = (p + 1) % 13;
                    const int ro = rr - 12;
                    if (ro >= 0) {
                        const int o = o0 + ro;   // always in [0,511]
                        *(float2*)&oi[(size_t)o * IMG_W + C + 2 * lane] =
                            make_float2(base + 16.f * fabsf(acc[sc][0]),
                                        base + 16.f * fabsf(acc[sc][1]));
                    }
                    acc[sc][0] = 0.f; acc[sc][1] = 0.f;   // ALWAYS reset
                }
                if (pre) strow(b ^ 1, pv);
            }
        }
    }
}

extern "C" void kernel_launch(void* const* d_in, const int* in_sizes, int n_in,
                              void* d_out, int out_size, void* d_ws, size_t ws_size,
                              hipStream_t stream) {
    const float* x = (const float*)d_in[0];
    const float* y = (const float*)d_in[1];
    float* out = (float*)d_out;
    double* ssum = (double*)d_ws;

    KTaps kt;
    {   // normalized gaussian win=11 sigma=1.5 (exp-based)
        double g[11], s = 0.0;
        for (int i = 0; i < 11; ++i) {
            const double d = (double)i - 5.0;
            g[i] = std::exp(-(d * d) / 4.5);
            s += g[i];
        }
        for (int i = 0; i < 11; ++i) kt.kw[i] = (float)(g[i] / s);
    }
    {   // erf-gaussian, tail=6 -> 13 taps, sigma=1.5, NOT normalized
        const double t = 0.70710678 / 1.5;
        for (int i = 0; i < 13; ++i) {
            const double xx = (double)i - 6.0;
            const double v = 0.5 * (std::erf(t * (xx + 0.5)) - std::erf(t * (xx - 0.5)));
            kt.ke[i] = (float)(v < 0.0 ? 0.0 : v);
        }
    }

    hipMemsetAsync(ssum, 0, sizeof(double), stream);

    ssim_band_kernel<<<dim3(1024), dim3(256), 0, stream>>>(x, y, ssum, kt);
    l1_band_kernel<<<dim3(1024), dim3(256), 0, stream>>>(x, y, ssum, out, kt);
}